// Round 4
// baseline (215.706 us; speedup 1.0000x reference)
//
#include <hip/hip_runtime.h>
#include <hip/hip_bf16.h>

#define BB 64
#define TT 4096
#define DD 128
#define KK 512

// key(-inf): bits(-inf)=0xFF800000, sign set -> ~u = 0x007FFFFF.
// All finite score keys are >= 0x00800000, so masked tokens sort strictly last.
#define KEY_NEG_INF 0x007FFFFFu

// ---------------------------------------------------------------------------
// Kernel 1: keys[b*T+t] = monotone_uint( dot(emb[b,t,:], W) + b0 ), masked -> key(-inf)
// Block = 256 threads = 4 waves = 256 contiguous tokens. Each wave: 2 tokens
// per iteration (half-wave each), float4 loads (16B/lane; wave covers 2
// contiguous 512B rows -> perfect coalescing). Butterfly reduce over the
// 32-lane half; scores staged in LDS; final key store is one fully-coalesced
// 1KB/block write with the mask applied there (coalesced mask load too).
// Double accumulation keeps the top-k set exact vs fp32 numpy (absmax 0.0).
// ---------------------------------------------------------------------------
__global__ __launch_bounds__(256) void k_scores(
    const float* __restrict__ emb, const int* __restrict__ mask,
    const float* __restrict__ W, const float* __restrict__ bias,
    unsigned int* __restrict__ keys_out)
{
    __shared__ unsigned int skeys[256];

    const int tid  = threadIdx.x;
    const int wave = tid >> 6;
    const int lane = tid & 63;
    const int half = lane >> 5;        // which token of the pair
    const int sub  = lane & 31;        // dim quarter within token
    const int t0_block = blockIdx.x * 256;
    const int t0_wave  = t0_block + wave * 64;

    const float4 w = ((const float4*)W)[sub];
    const double w0 = (double)w.x, w1 = (double)w.y, w2 = (double)w.z, w3 = (double)w.w;
    const double b0 = (double)bias[0];

#pragma unroll 8
    for (int i = 0; i < 32; ++i) {
        const int t = t0_wave + 2 * i + half;          // global token in [0, B*T)
        const float4 e = ((const float4*)emb)[(size_t)t * 32 + sub];
        double s = (double)e.x * w0 + (double)e.y * w1
                 + (double)e.z * w2 + (double)e.w * w3;
        s += __shfl_xor(s, 16, 64);
        s += __shfl_xor(s,  8, 64);
        s += __shfl_xor(s,  4, 64);
        s += __shfl_xor(s,  2, 64);
        s += __shfl_xor(s,  1, 64);
        if (sub == 0) {
            const float val = (float)(s + b0);
            const unsigned int u = __float_as_uint(val);
            skeys[wave * 64 + 2 * i + half] = (u & 0x80000000u) ? ~u : (u | 0x80000000u);
        }
    }
    __syncthreads();
    const int t = t0_block + tid;
    unsigned int key = skeys[tid];
    if (!mask[t]) key = KEY_NEG_INF;                   // coalesced mask load
    keys_out[t] = key;                                 // coalesced key store
}

// ---------------------------------------------------------------------------
// Kernel 2 (fused select+gather): per-row exact top-K (ties -> lower index),
// selected indices in ASCENDING token order; writes gathered mask (0/1 floats)
// AND gathers the selected embedding rows (emb is L3-resident after k_scores).
// One 1024-thread block (16 waves) per row. 4-pass MSB radix select; 16-way
// privatized histograms; 256-bin suffix scan by wave 0 in registers.
// ---------------------------------------------------------------------------
__global__ __launch_bounds__(1024) void k_selgath(
    const unsigned int* __restrict__ keys_in, const int* __restrict__ mask,
    const float* __restrict__ emb,
    float* __restrict__ out_sel, float* __restrict__ mask_out)
{
    __shared__ unsigned int keys[TT];           // 16 KB
    __shared__ unsigned int hist[16][257];      // ~16.4 KB, per-wave ways
    __shared__ unsigned int hist_final[256];
    __shared__ unsigned int wsum[16];
    __shared__ unsigned int bcast[2];           // [0]=chosen bin, [1]=new count_above
    __shared__ int idx_l[KK];                   // pos -> token map (2 KB)

    const int row  = blockIdx.x;
    const int tid  = threadIdx.x;
    const int wv   = tid >> 6;
    const int lane = tid & 63;
    const unsigned int* krow = keys_in + (size_t)row * TT;
    const int*          mrow = mask    + (size_t)row * TT;

    // Coalesced uint4 load of this thread's 4 keys.
    const uint4 kv = ((const uint4*)krow)[tid];
    ((uint4*)keys)[tid] = kv;

    unsigned int prefix = 0;        // high bytes decided so far
    unsigned int count_above = 0;   // #keys strictly greater than current range
    for (int pass = 0; pass < 4; ++pass) {
        const int shift = 24 - 8 * pass;
        for (int i = tid; i < 16 * 257; i += 1024) ((unsigned int*)hist)[i] = 0;
        __syncthreads();
#pragma unroll
        for (int i = 0; i < 4; ++i) {
            const unsigned int k = keys[tid * 4 + i];
            const bool in_group = (pass == 0) || ((k >> (shift + 8)) == prefix);
            if (in_group) atomicAdd(&hist[wv][(k >> shift) & 0xFFu], 1u);
        }
        __syncthreads();
        if (tid < 256) {
            unsigned int s = 0;
#pragma unroll
            for (int w = 0; w < 16; ++w) s += hist[w][tid];
            hist_final[tid] = s;
        }
        __syncthreads();
        if (wv == 0) {
            // Descending-bin order: position p = 4*lane+j handles bin 255-p.
            unsigned int v[4], c[4];
            unsigned int run = 0;
#pragma unroll
            for (int j = 0; j < 4; ++j) {
                v[j] = hist_final[255 - (4 * lane + j)];
                run += v[j];
                c[j] = run;                     // lane-local inclusive
            }
            unsigned int scan = run;
#pragma unroll
            for (int off = 1; off < 64; off <<= 1) {
                const unsigned int u = __shfl_up(scan, off, 64);
                if (lane >= off) scan += u;
            }
            const unsigned int excl_w = scan - run;  // keys in higher bins than this lane's range
#pragma unroll
            for (int j = 0; j < 4; ++j) {
                const unsigned int incl = excl_w + c[j];   // #keys with byte >= bin
                const unsigned int excl = incl - v[j];     // #keys with byte >  bin
                if (count_above + incl >= KK && count_above + excl < KK) {
                    bcast[0] = 255u - (unsigned int)(4 * lane + j);
                    bcast[1] = count_above + excl;
                }
            }
        }
        __syncthreads();
        prefix = (prefix << 8) | bcast[0];
        count_above = bcast[1];
        // No extra barrier: next pass's hist-zero barrier protects bcast reuse.
    }
    const unsigned int vstar = prefix;            // exact key of Kth largest
    const unsigned int need  = KK - count_above;  // #ties to take, lowest index first

    // ---- emit selected positions (ascending token order) into LDS + mask_out ----
    unsigned int gt = 0, eq = 0;
#pragma unroll
    for (int i = 0; i < 4; ++i) {
        const unsigned int k = keys[tid * 4 + i];
        gt += (k > vstar);
        eq += (k == vstar);
    }
    unsigned int packed = (gt << 16) | eq;        // counts <= 4096, no overflow
    unsigned int scan = packed;
#pragma unroll
    for (int off = 1; off < 64; off <<= 1) {
        const unsigned int u = __shfl_up(scan, off, 64);
        if (lane >= off) scan += u;
    }
    if (lane == 63) wsum[wv] = scan;
    __syncthreads();
    unsigned int add = 0;
    for (int w = 0; w < wv; ++w) add += wsum[w];  // LDS broadcast reads
    const unsigned int before = scan - packed + add;  // block-exclusive prefix
    unsigned int gt_b = before >> 16;
    unsigned int eq_b = before & 0xFFFFu;
#pragma unroll
    for (int i = 0; i < 4; ++i) {
        const int t = tid * 4 + i;
        const unsigned int k = keys[t];
        if (k > vstar) {
            const unsigned int pos = gt_b + (eq_b < need ? eq_b : need);
            idx_l[pos] = t;
            mask_out[row * KK + pos] = mrow[t] ? 1.0f : 0.0f;
            gt_b++;
        } else if (k == vstar) {
            if (eq_b < need) {
                const unsigned int pos = gt_b + eq_b;
                idx_l[pos] = t;
                mask_out[row * KK + pos] = mrow[t] ? 1.0f : 0.0f;
            }
            eq_b++;
        }
    }
    __syncthreads();

    // ---- gather: out_sel[row, j, :] = emb[row, idx_l[j], :] ----
    // Half-wave per selected row: lanes 0-31 -> row j, lanes 32-63 -> row j+1.
    const int half = lane >> 5;
    const int sub  = lane & 31;
    for (int jj = wv * 2; jj < KK; jj += 32) {
        const int j = jj + half;
        const int t = idx_l[j];
        const float4 v = ((const float4*)(emb + ((size_t)row * TT + t) * DD))[sub];
        ((float4*)(out_sel + ((size_t)row * KK + j) * DD))[sub] = v;
    }
}

extern "C" void kernel_launch(void* const* d_in, const int* in_sizes, int n_in,
                              void* d_out, int out_size, void* d_ws, size_t ws_size,
                              hipStream_t stream)
{
    const float* emb  = (const float*)d_in[0];   // (B,T,D) fp32
    const int*   mask = (const int*)d_in[1];     // (B,T) bool -> int32 0/1
    // d_in[2] = k (int scalar) -- fixed at 512 for this problem instance
    const float* W    = (const float*)d_in[3];   // (D,)
    const float* bias = (const float*)d_in[4];   // (1,)

    float* out_sel  = (float*)d_out;                        // B*K*D floats
    float* out_mask = (float*)d_out + (size_t)BB * KK * DD; // B*K floats

    unsigned int* keys = (unsigned int*)d_ws;               // B*T uints (1 MB)

    k_scores<<<BB * TT / 256, 256, 0, stream>>>(emb, mask, W, bias, keys);
    k_selgath<<<BB, 1024, 0, stream>>>(keys, mask, emb, out_sel, out_mask);
}

// Round 5
// 215.510 us; speedup vs baseline: 1.0009x; 1.0009x over previous
//
#include <hip/hip_runtime.h>
#include <hip/hip_bf16.h>

#define BB 64
#define TT 4096
#define DD 128
#define KK 512

// key(-inf): bits(-inf)=0xFF800000, sign set -> ~u = 0x007FFFFF.
// All finite score keys are >= 0x00800000, so masked tokens sort strictly last.
#define KEY_NEG_INF 0x007FFFFFu

// ---------------------------------------------------------------------------
// Kernel 1: keys[b*T+t] = monotone_uint( dot(emb[b,t,:], W) + b0 ), masked -> key(-inf)
// Block = 256 threads = 4 waves = 256 contiguous tokens. Each wave: 2 tokens
// per iteration (half-wave each), float4 loads (16B/lane; wave covers 2
// contiguous 512B rows -> perfect coalescing). Butterfly reduce over the
// 32-lane half; keys staged in LDS; final store is one fully-coalesced
// 1KB/block write with the mask applied there (coalesced mask load too).
// Double accumulation keeps the top-k set exact vs fp32 numpy (absmax 0.0).
// ---------------------------------------------------------------------------
__global__ __launch_bounds__(256) void k_scores(
    const float* __restrict__ emb, const int* __restrict__ mask,
    const float* __restrict__ W, const float* __restrict__ bias,
    unsigned int* __restrict__ keys_out)
{
    __shared__ unsigned int skeys[256];

    const int tid  = threadIdx.x;
    const int wave = tid >> 6;
    const int lane = tid & 63;
    const int half = lane >> 5;        // which token of the pair
    const int sub  = lane & 31;        // dim quarter within token
    const int t0_block = blockIdx.x * 256;
    const int t0_wave  = t0_block + wave * 64;

    const float4 w = ((const float4*)W)[sub];
    const double w0 = (double)w.x, w1 = (double)w.y, w2 = (double)w.z, w3 = (double)w.w;
    const double b0 = (double)bias[0];

#pragma unroll 8
    for (int i = 0; i < 32; ++i) {
        const int t = t0_wave + 2 * i + half;          // global token in [0, B*T)
        const float4 e = ((const float4*)emb)[(size_t)t * 32 + sub];
        double s = (double)e.x * w0 + (double)e.y * w1
                 + (double)e.z * w2 + (double)e.w * w3;
        s += __shfl_xor(s, 16, 64);
        s += __shfl_xor(s,  8, 64);
        s += __shfl_xor(s,  4, 64);
        s += __shfl_xor(s,  2, 64);
        s += __shfl_xor(s,  1, 64);
        if (sub == 0) {
            const float val = (float)(s + b0);
            const unsigned int u = __float_as_uint(val);
            skeys[wave * 64 + 2 * i + half] = (u & 0x80000000u) ? ~u : (u | 0x80000000u);
        }
    }
    __syncthreads();
    const int t = t0_block + tid;
    unsigned int key = skeys[tid];
    if (!mask[t]) key = KEY_NEG_INF;                   // coalesced mask load
    keys_out[t] = key;                                 // coalesced key store
}

// ---------------------------------------------------------------------------
// Kernel 2: per-row exact top-K (ties -> lower index); emits selected token
// indices in ASCENDING token order + gathered mask (0/1 floats), both staged
// in LDS and written fully coalesced. One 1024-thread block (16 waves) per
// row. 4-pass MSB radix select; 16-way privatized histograms; 256-bin suffix
// scan by wave 0 alone in registers (wave-synchronous).
// ---------------------------------------------------------------------------
__global__ __launch_bounds__(1024) void k_select(
    const unsigned int* __restrict__ keys_in, const int* __restrict__ mask,
    int* __restrict__ idx_out, float* __restrict__ mask_out)
{
    __shared__ unsigned int keys[TT];           // 16 KB
    __shared__ unsigned int hist[16][257];      // ~16.4 KB, per-wave ways
    __shared__ unsigned int hist_final[256];
    __shared__ unsigned int wsum[16];
    __shared__ unsigned int bcast[2];           // [0]=chosen bin, [1]=new count_above
    __shared__ int   idx_l[KK];                 // pos -> token (2 KB)
    __shared__ float msk_l[KK];                 // pos -> mask  (2 KB)

    const int row  = blockIdx.x;
    const int tid  = threadIdx.x;
    const int wv   = tid >> 6;
    const int lane = tid & 63;
    const unsigned int* krow = keys_in + (size_t)row * TT;
    const int*          mrow = mask    + (size_t)row * TT;

    // Coalesced uint4 load of this thread's 4 keys.
    const uint4 kv = ((const uint4*)krow)[tid];
    ((uint4*)keys)[tid] = kv;

    unsigned int prefix = 0;        // high bytes decided so far
    unsigned int count_above = 0;   // #keys strictly greater than current range
    for (int pass = 0; pass < 4; ++pass) {
        const int shift = 24 - 8 * pass;
        for (int i = tid; i < 16 * 257; i += 1024) ((unsigned int*)hist)[i] = 0;
        __syncthreads();
#pragma unroll
        for (int i = 0; i < 4; ++i) {
            const unsigned int k = keys[tid * 4 + i];
            const bool in_group = (pass == 0) || ((k >> (shift + 8)) == prefix);
            if (in_group) atomicAdd(&hist[wv][(k >> shift) & 0xFFu], 1u);
        }
        __syncthreads();
        if (tid < 256) {
            unsigned int s = 0;
#pragma unroll
            for (int w = 0; w < 16; ++w) s += hist[w][tid];
            hist_final[tid] = s;
        }
        __syncthreads();
        if (wv == 0) {
            // Descending-bin order: position p = 4*lane+j handles bin 255-p.
            unsigned int v[4], c[4];
            unsigned int run = 0;
#pragma unroll
            for (int j = 0; j < 4; ++j) {
                v[j] = hist_final[255 - (4 * lane + j)];
                run += v[j];
                c[j] = run;                     // lane-local inclusive
            }
            unsigned int scan = run;
#pragma unroll
            for (int off = 1; off < 64; off <<= 1) {
                const unsigned int u = __shfl_up(scan, off, 64);
                if (lane >= off) scan += u;
            }
            const unsigned int excl_w = scan - run;  // keys in higher bins than this lane's range
#pragma unroll
            for (int j = 0; j < 4; ++j) {
                const unsigned int incl = excl_w + c[j];   // #keys with byte >= bin
                const unsigned int excl = incl - v[j];     // #keys with byte >  bin
                if (count_above + incl >= KK && count_above + excl < KK) {
                    bcast[0] = 255u - (unsigned int)(4 * lane + j);
                    bcast[1] = count_above + excl;
                }
            }
        }
        __syncthreads();
        prefix = (prefix << 8) | bcast[0];
        count_above = bcast[1];
        // No extra barrier: next pass's hist-zero barrier protects bcast reuse.
    }
    const unsigned int vstar = prefix;            // exact key of Kth largest
    const unsigned int need  = KK - count_above;  // #ties to take, lowest index first

    // ---- emit selected positions (ascending token order) into LDS ----
    unsigned int gt = 0, eq = 0;
#pragma unroll
    for (int i = 0; i < 4; ++i) {
        const unsigned int k = keys[tid * 4 + i];
        gt += (k > vstar);
        eq += (k == vstar);
    }
    unsigned int packed = (gt << 16) | eq;        // counts <= 4096, no overflow
    unsigned int scan = packed;
#pragma unroll
    for (int off = 1; off < 64; off <<= 1) {
        const unsigned int u = __shfl_up(scan, off, 64);
        if (lane >= off) scan += u;
    }
    if (lane == 63) wsum[wv] = scan;
    __syncthreads();
    unsigned int add = 0;
    for (int w = 0; w < wv; ++w) add += wsum[w];  // LDS broadcast reads
    const unsigned int before = scan - packed + add;  // block-exclusive prefix
    unsigned int gt_b = before >> 16;
    unsigned int eq_b = before & 0xFFFFu;
#pragma unroll
    for (int i = 0; i < 4; ++i) {
        const int t = tid * 4 + i;
        const unsigned int k = keys[t];
        if (k > vstar) {
            const unsigned int pos = gt_b + (eq_b < need ? eq_b : need);
            idx_l[pos] = t;
            msk_l[pos] = mrow[t] ? 1.0f : 0.0f;
            gt_b++;
        } else if (k == vstar) {
            if (eq_b < need) {
                const unsigned int pos = gt_b + eq_b;
                idx_l[pos] = t;
                msk_l[pos] = mrow[t] ? 1.0f : 0.0f;
            }
            eq_b++;
        }
    }
    __syncthreads();

    // ---- coalesced dump of idx + mask ----
    if (tid < KK) {
        idx_out[row * KK + tid]  = idx_l[tid];
        mask_out[row * KK + tid] = msk_l[tid];
    }
}

// ---------------------------------------------------------------------------
// Kernel 3: out[b,j,:] = emb[b, idx[b*K+j], :]
// 32 lanes x float4 = 128 floats per selected row; 8 rows per 256-thread
// block; 4096 blocks -> full-GPU width for the 34 MB of L3-warm traffic.
// ---------------------------------------------------------------------------
__global__ __launch_bounds__(256) void k_gather(
    const float* __restrict__ emb, const int* __restrict__ idx,
    float* __restrict__ out)
{
    const int gp   = blockIdx.x * 8 + (threadIdx.x >> 5);  // selected-row index in [0, B*K)
    const int lane = threadIdx.x & 31;
    const int b = gp >> 9;                                  // / KK
    const int t = idx[gp];
    const float4* src = (const float4*)(emb + ((size_t)b * TT + t) * DD);
    float4*       dst = (float4*)(out + (size_t)gp * DD);
    dst[lane] = src[lane];
}

extern "C" void kernel_launch(void* const* d_in, const int* in_sizes, int n_in,
                              void* d_out, int out_size, void* d_ws, size_t ws_size,
                              hipStream_t stream)
{
    const float* emb  = (const float*)d_in[0];   // (B,T,D) fp32
    const int*   mask = (const int*)d_in[1];     // (B,T) bool -> int32 0/1
    // d_in[2] = k (int scalar) -- fixed at 512 for this problem instance
    const float* W    = (const float*)d_in[3];   // (D,)
    const float* bias = (const float*)d_in[4];   // (1,)

    float* out_sel  = (float*)d_out;                        // B*K*D floats
    float* out_mask = (float*)d_out + (size_t)BB * KK * DD; // B*K floats

    unsigned int* keys = (unsigned int*)d_ws;                                   // B*T uints (1 MB)
    int*          idx  = (int*)((char*)d_ws + (size_t)BB * TT * sizeof(unsigned int)); // B*K ints

    k_scores<<<BB * TT / 256, 256, 0, stream>>>(emb, mask, W, bias, keys);
    k_select<<<BB, 1024, 0, stream>>>(keys, mask, idx, out_mask);
    k_gather<<<BB * KK / 8, 256, 0, stream>>>(emb, idx, out_sel);
}